// Round 8
// baseline (577.428 us; speedup 1.0000x reference)
//
#include <hip/hip_runtime.h>

// Problem constants (AttentionalCopula)
constexpr int kB = 16, kD = 256, kNH = 512, kNV = 256, kW = 768;
constexpr int kL = 4, kH = 8, kA = 64, kHA = 512, kM = 512, kR = 128;
constexpr int kKP = 288;  // K=257 zero-padded to multiple of 32
constexpr int kRows = kB * kNV;  // 4096

typedef __bf16 bf16x8 __attribute__((ext_vector_type(8)));
typedef __bf16 bf16x4 __attribute__((ext_vector_type(4)));
typedef float f32x4 __attribute__((ext_vector_type(4)));

__device__ inline void load_lds16(const __bf16* g, __bf16* l) {
  __builtin_amdgcn_global_load_lds(
      (const __attribute__((address_space(1))) void*)g,
      (__attribute__((address_space(3))) void*)l, 16, 0, 0);
}

// ---------------- merged prep kernel (1 launch) ----------------
constexpr int kP1 = kB * kW * kKP;        // ki
constexpr int kP2 = 4096 * kKP;           // kv weights
constexpr int kP3 = 12 * 512 * 512;       // ff weights
constexpr int kP4 = 200704;               // ds_wt, de_wt, kvb
constexpr int kP5 = 65536;                // stats zero (8 bufs x 4096 x 2)
constexpr int kPT = kP1 + kP2 + kP3 + kP4 + kP5;

__global__ void prep_kernel(const float* __restrict__ hist,
                            const float* __restrict__ hist_u,
                            const float* __restrict__ pred,
                            const float* __restrict__ pred_u,
                            const float* __restrict__ kw,
                            const float* __restrict__ vw,
                            const float* __restrict__ w1,
                            const float* __restrict__ w2,
                            const float* __restrict__ w3,
                            const float* __restrict__ ds_w,
                            const float* __restrict__ de_w,
                            const float* __restrict__ key_b,
                            const float* __restrict__ val_b,
                            __bf16* __restrict__ ki,
                            __bf16* __restrict__ kvwt,
                            __bf16* __restrict__ ffwt,
                            __bf16* __restrict__ ds_wt,
                            __bf16* __restrict__ de_wt,
                            float* __restrict__ kvb,
                            float* __restrict__ stats) {
  int i = blockIdx.x * 256 + threadIdx.x;
  if (i < kP1) {
    int d = i % kKP;
    int bw = i / kKP;
    int w = bw % kW;
    int b = bw / kW;
    float v = 0.f;
    if (d < 257) {
      if (w < kNH)
        v = (d < kD) ? hist[((size_t)b * kNH + w) * kD + d] : hist_u[b * kNH + w];
      else {
        int p = w - kNH;
        v = (d < kD) ? pred[((size_t)b * kNV + p) * kD + d] : pred_u[b * kNV + p];
      }
    }
    ki[i] = (__bf16)v;
  } else if (i < kP1 + kP2) {
    int j = i - kP1;
    int d = j % kKP;
    int c = j / kKP;
    float v = 0.f;
    if (d < 257) {
      bool isv = c >= 2048;
      int cc = isv ? c - 2048 : c;
      int l = cc >> 9, rest = cc & 511;
      int h = rest >> 6, a = rest & 63;
      size_t src = (((size_t)l * kH + h) * 257 + d) * kA + a;
      v = isv ? vw[src] : kw[src];
    }
    kvwt[j] = (__bf16)v;
  } else if (i < kP1 + kP2 + kP3) {
    int j = i - kP1 - kP2;
    int k = j & 511;
    int n = (j >> 9) & 511;
    int mat = j >> 18;
    int l = mat / 3, which = mat % 3;
    const float* src = which == 0 ? w1 : which == 1 ? w2 : w3;
    ffwt[j] = (__bf16)src[((size_t)l * 512 + k) * 512 + n];
  } else if (i < kP1 + kP2 + kP3 + kP4) {
    int j = i - kP1 - kP2 - kP3;
    if (j < 131072) {
      int n = j >> 8, k = j & 255;
      ds_wt[j] = (__bf16)ds_w[k * 512 + n];
    } else if (j < 196608) {
      int jj = j - 131072;
      int n = jj >> 9, k = jj & 511;
      de_wt[jj] = (__bf16)de_w[k * 128 + n];
    } else {
      int c = j - 196608;  // 0..4095
      bool isv = c >= 2048;
      int cc = isv ? c - 2048 : c;
      int l = cc >> 9, rest = cc & 511;
      kvb[c] = isv ? val_b[l * 512 + rest] : key_b[l * 512 + rest];
    }
  } else if (i < kPT) {
    stats[i - kP1 - kP2 - kP3 - kP4] = 0.f;
  }
}

// ---------------- generic bf16 MFMA GEMM core ----------------
template <int BN, int OMODE, bool RELU, bool KIMAP, bool BIASROW>
__device__ __forceinline__ void gemm_core(
    int bxv, int byv, const __bf16* __restrict__ A,
    const __bf16* __restrict__ Bt, const float* __restrict__ bias,
    void* __restrict__ Cout, int K, int lda, int ldc,
    __bf16* As, __bf16* Bs) {
  constexpr int JN = BN / 32;
  constexpr int BROWS = BN / 4;
  const int t = threadIdx.x;
  const int wid = t >> 6;
  const int lane = t & 63;
  const int bm = byv * 128;
  const int bn = bxv * BN;
  const int wm = (wid >> 1) * 64;
  const int wn = (wid & 1) * (BN / 2);
  const int sr = lane >> 2, sc = lane & 3;
  const int skey = (sr >> 1) & 3;
  const int abase = KIMAP ? ((bm >> 8) * 768 + 512 + (bm & 255)) : bm;
  const __bf16* Ag = A + (size_t)(abase + wid * 32 + sr) * lda + (sc ^ skey) * 8;
  const __bf16* Bg = Bt + (size_t)(bn + wid * BROWS + sr) * K + (sc ^ skey) * 8;
  __bf16* AsW = As + (wid * 32) * 32;
  __bf16* BsW = Bs + (wid * BROWS) * 32;

  f32x4 acc[4][JN] = {};
  const int q = lane >> 4, mr = lane & 15;
  const int rkey = (mr >> 1) & 3;
  for (int k0 = 0; k0 < K; k0 += 32) {
    if (k0) __syncthreads();
    load_lds16(Ag + k0, AsW);
    load_lds16(Ag + (size_t)16 * lda + k0, AsW + 16 * 32);
    load_lds16(Bg + k0, BsW);
    if (BN == 128) load_lds16(Bg + (size_t)16 * K + k0, BsW + 16 * 32);
    __syncthreads();
    bf16x8 af[4], bfr[JN];
#pragma unroll
    for (int i = 0; i < 4; ++i)
      af[i] = *(const bf16x8*)(As + (wm + i * 16 + mr) * 32 + (q ^ rkey) * 8);
#pragma unroll
    for (int j = 0; j < JN; ++j)
      bfr[j] = *(const bf16x8*)(Bs + (wn + j * 16 + mr) * 32 + (q ^ rkey) * 8);
#pragma unroll
    for (int i = 0; i < 4; ++i)
#pragma unroll
      for (int j = 0; j < JN; ++j)
        acc[i][j] = __builtin_amdgcn_mfma_f32_16x16x32_bf16(af[i], bfr[j],
                                                            acc[i][j], 0, 0, 0);
  }
#pragma unroll
  for (int j = 0; j < JN; ++j) {
    int col = bn + wn + j * 16 + mr;
    float bscol = BIASROW ? 0.f : bias[col];
#pragma unroll
    for (int i = 0; i < 4; ++i) {
      int row0 = bm + wm + i * 16 + q * 4;
#pragma unroll
      for (int r = 0; r < 4; ++r) {
        float v = acc[i][j][r] + (BIASROW ? bias[row0 + r] : bscol);
        if (RELU) v = fmaxf(v, 0.f);
        size_t idx = (size_t)(row0 + r) * ldc + col;
        if (OMODE == 0)
          ((float*)Cout)[idx] = v;
        else
          ((__bf16*)Cout)[idx] = (__bf16)v;
      }
    }
  }
}

// ---------------- fused ds + keys + vT GEMM (one launch, 3328 blocks) ----------------
__global__ __launch_bounds__(256) void gemm3_kernel(
    const __bf16* __restrict__ ki, const __bf16* __restrict__ ds_wt,
    const float* __restrict__ ds_b, float* __restrict__ S,
    const __bf16* __restrict__ kv_wt, const float* __restrict__ kvb,
    __bf16* __restrict__ kvs_k, __bf16* __restrict__ vT) {
  __shared__ __bf16 smem[8192];
  __bf16* As = smem;
  __bf16* Bs = smem + 4096;
  int bid = blockIdx.x;
  if (bid < 256) {
    // ds: S = pred @ ds_w + b  [4096 x 512], K=256, A rows inside ki
    gemm_core<64, 0, false, true, false>(bid & 7, bid >> 3, ki, ds_wt, ds_b, S,
                                         256, kKP, 512, As, Bs);
  } else if (bid < 1792) {
    // keys: [12288 x 2048]
    int b2 = bid - 256;
    gemm_core<128, 1, false, false, false>(b2 & 15, b2 >> 4, ki, kv_wt, kvb,
                                           kvs_k, kKP, kKP, 2048, As, Bs);
  } else {
    // values^T: [2048 x 12288] = Wv^T @ ki^T (bias per row)
    int b3 = bid - 1792;
    gemm_core<128, 1, false, false, true>(b3 % 96, b3 / 96,
                                          kv_wt + (size_t)2048 * kKP, ki,
                                          kvb + 2048, vT, kKP, kKP, 12288, As,
                                          Bs);
  }
}

// ---------------- MFMA flash attention with fused LN2-on-load + residual ----------------
// l==0: Q = S raw. l>0: Q = LN(S; statsPrev, g2, b2).
// Epilogue: S[slice] = base + O/l  (base = raw or LN'd), atomicAdd LN1 stats.
__global__ __launch_bounds__(256) void attn_kernel(
    float* __restrict__ S, const __bf16* __restrict__ kvs_k,
    const __bf16* __restrict__ vT, const float* __restrict__ statsPrev,
    float* __restrict__ statsA, const float* __restrict__ g2,
    const float* __restrict__ b2, int l) {
  const int b = blockIdx.z, h = blockIdx.y, qt = blockIdx.x;
  __shared__ __bf16 Ks[64 * 72];
  __shared__ __bf16 Vt[64 * 72];
  __shared__ __bf16 Ps[64 * 72];
  const int t = threadIdx.x;
  const int w = t >> 6, lane = t & 63;
  const int quad = lane >> 4, mr = lane & 15;
  // ---- Q load (+LN) ----
  bf16x8 aq[2];
  {
    int row = b * kNV + qt * 64 + w * 16 + mr;
    const float* sp = S + (size_t)row * kHA + h * kA + quad * 8;
    float4 x0 = *(const float4*)sp;
    float4 x1 = *(const float4*)(sp + 4);
    float4 x2 = *(const float4*)(sp + 32);
    float4 x3 = *(const float4*)(sp + 36);
    float xs[16] = {x0.x, x0.y, x0.z, x0.w, x1.x, x1.y, x1.z, x1.w,
                    x2.x, x2.y, x2.z, x2.w, x3.x, x3.y, x3.z, x3.w};
    if (l > 0) {
      float s0 = statsPrev[2 * row], s1 = statsPrev[2 * row + 1];
      float m = s0 * (1.f / kHA);
      float inv = rsqrtf(s1 * (1.f / kHA) - m * m + 1e-5f);
      int cbase = h * kA + quad * 8;
#pragma unroll
      for (int e = 0; e < 8; ++e) {
        xs[e] = (xs[e] - m) * inv * g2[cbase + e] + b2[cbase + e];
        xs[8 + e] = (xs[8 + e] - m) * inv * g2[cbase + 32 + e] + b2[cbase + 32 + e];
      }
    }
#pragma unroll
    for (int e = 0; e < 8; ++e) {
      aq[0][e] = (__bf16)xs[e];
      aq[1][e] = (__bf16)xs[8 + e];
    }
  }
  f32x4 o[4] = {};
  float m_ = -1e30f, l_ = 0.f;
  const int cmax = kNH + qt * 64;
  const int pr = t >> 2, pc = t & 3;
  const __bf16* kbase = kvs_k + ((size_t)(b * kW + pr) * 2048 + l * 512 + h * kA);
  const __bf16* vbase = vT + (size_t)(l * 512 + h * kA + pr) * 12288 + b * kW;
  bf16x8 kc0, kc1, vc0, vc1;
  kc0 = *(const bf16x8*)(kbase + pc * 8);
  kc1 = *(const bf16x8*)(kbase + pc * 8 + 32);
  vc0 = *(const bf16x8*)(vbase + pc * 16);
  vc1 = *(const bf16x8*)(vbase + pc * 16 + 8);
  for (int c0 = 0; c0 <= cmax; c0 += 64) {
    __syncthreads();
    *(bf16x8*)&Ks[pr * 72 + pc * 8] = kc0;
    *(bf16x8*)&Ks[pr * 72 + pc * 8 + 32] = kc1;
    *(bf16x8*)&Vt[pr * 72 + pc * 16] = vc0;
    *(bf16x8*)&Vt[pr * 72 + pc * 16 + 8] = vc1;
    __syncthreads();
    if (c0 + 64 <= cmax) {
      const __bf16* kp = kbase + (size_t)(c0 + 64) * 2048;
      const __bf16* vp = vbase + c0 + 64;
      kc0 = *(const bf16x8*)(kp + pc * 8);
      kc1 = *(const bf16x8*)(kp + pc * 8 + 32);
      vc0 = *(const bf16x8*)(vp + pc * 16);
      vc1 = *(const bf16x8*)(vp + pc * 16 + 8);
    }
    f32x4 s[4];
#pragma unroll
    for (int j = 0; j < 4; ++j) {
      bf16x8 ak0 = *(const bf16x8*)&Ks[(j * 16 + mr) * 72 + quad * 8];
      bf16x8 ak1 = *(const bf16x8*)&Ks[(j * 16 + mr) * 72 + quad * 8 + 32];
      f32x4 z = {};
      z = __builtin_amdgcn_mfma_f32_16x16x32_bf16(ak0, aq[0], z, 0, 0, 0);
      z = __builtin_amdgcn_mfma_f32_16x16x32_bf16(ak1, aq[1], z, 0, 0, 0);
      s[j] = z;
    }
    const int lim = cmax - c0;
    float sv[16], mx = -1e30f;
#pragma unroll
    for (int j = 0; j < 4; ++j)
#pragma unroll
      for (int r = 0; r < 4; ++r) {
        int p = j * 16 + quad * 4 + r;
        float x = (p < lim + mr) ? s[j][r] * 0.125f : -1e30f;
        sv[j * 4 + r] = x;
        mx = fmaxf(mx, x);
      }
    mx = fmaxf(mx, __shfl_xor(mx, 16));
    mx = fmaxf(mx, __shfl_xor(mx, 32));
    float mnew = fmaxf(m_, mx);
    float corr = __expf(m_ - mnew);
    float rs = 0.f;
#pragma unroll
    for (int i = 0; i < 16; ++i) {
      sv[i] = __expf(sv[i] - mnew);
      rs += sv[i];
    }
    rs += __shfl_xor(rs, 16);
    rs += __shfl_xor(rs, 32);
    l_ = l_ * corr + rs;
    m_ = mnew;
#pragma unroll
    for (int j = 0; j < 4; ++j) {
      bf16x4 pk = {(__bf16)sv[j * 4 + 0], (__bf16)sv[j * 4 + 1],
                   (__bf16)sv[j * 4 + 2], (__bf16)sv[j * 4 + 3]};
      *(bf16x4*)&Ps[(w * 16 + mr) * 72 + j * 16 + quad * 4] = pk;
    }
#pragma unroll
    for (int r = 0; r < 4; ++r) {
      float cr = __shfl(corr, quad * 4 + r);
#pragma unroll
      for (int j = 0; j < 4; ++j) o[j][r] *= cr;
    }
    bf16x8 ap0 = *(const bf16x8*)&Ps[(w * 16 + mr) * 72 + quad * 8];
    bf16x8 ap1 = *(const bf16x8*)&Ps[(w * 16 + mr) * 72 + quad * 8 + 32];
#pragma unroll
    for (int j = 0; j < 4; ++j) {
      bf16x8 b0 = *(const bf16x8*)&Vt[(j * 16 + mr) * 72 + quad * 8];
      bf16x8 b1 = *(const bf16x8*)&Vt[(j * 16 + mr) * 72 + quad * 8 + 32];
      o[j] = __builtin_amdgcn_mfma_f32_16x16x32_bf16(ap0, b0, o[j], 0, 0, 0);
      o[j] = __builtin_amdgcn_mfma_f32_16x16x32_bf16(ap1, b1, o[j], 0, 0, 0);
    }
  }
  // ---- epilogue: S = base + O/l ; atomic LN1 stats ----
  float invl = 1.f / l_;
#pragma unroll
  for (int r = 0; r < 4; ++r) {
    float ir = __shfl(invl, quad * 4 + r);
    int row = b * kNV + qt * 64 + w * 16 + quad * 4 + r;
    float m = 0.f, inv = 0.f;
    if (l > 0) {
      float s0 = statsPrev[2 * row], s1 = statsPrev[2 * row + 1];
      m = s0 * (1.f / kHA);
      inv = rsqrtf(s1 * (1.f / kHA) - m * m + 1e-5f);
    }
    float ps = 0.f, pq = 0.f;
#pragma unroll
    for (int j = 0; j < 4; ++j) {
      int col = h * kA + j * 16 + mr;
      size_t idx = (size_t)row * kHA + col;
      float sval = S[idx];
      float base = (l > 0) ? ((sval - m) * inv * g2[col] + b2[col]) : sval;
      float v = base + o[j][r] * ir;
      S[idx] = v;
      ps += v;
      pq += v * v;
    }
    ps += __shfl_xor(ps, 1); pq += __shfl_xor(pq, 1);
    ps += __shfl_xor(ps, 2); pq += __shfl_xor(pq, 2);
    ps += __shfl_xor(ps, 4); pq += __shfl_xor(pq, 4);
    ps += __shfl_xor(ps, 8); pq += __shfl_xor(pq, 8);
    if (mr == 0) {
      atomicAdd(&statsA[2 * row], ps);
      atomicAdd(&statsA[2 * row + 1], pq);
    }
  }
}

// ---------------- ff1: A = LN1(S) on the fly; GEMM + relu -> bf16 ----------------
__global__ __launch_bounds__(256) void ff1_ln_gemm_kernel(
    const float* __restrict__ S, const float* __restrict__ stats,
    const float* __restrict__ g, const float* __restrict__ be,
    const __bf16* __restrict__ Bt, const float* __restrict__ bias,
    __bf16* __restrict__ Cout) {
  __shared__ __bf16 Bs[64 * 32];
  __shared__ float gb[1024];
  const int t = threadIdx.x;
  for (int i = t; i < 512; i += 256) {
    gb[i] = g[i];
    gb[512 + i] = be[i];
  }
  const int wid = t >> 6, lane = t & 63;
  const int quad = lane >> 4, mr = lane & 15;
  const int bm = blockIdx.y * 128, bn = blockIdx.x * 64;
  const int wm = (wid >> 1) * 64, wn = (wid & 1) * 32;
  const int sr = lane >> 2, sc = lane & 3;
  const int skey = (sr >> 1) & 3;
  const __bf16* Bg = Bt + (size_t)(bn + wid * 16 + sr) * 512 + (sc ^ skey) * 8;
  __bf16* BsW = Bs + (wid * 16) * 32;
  float mean_[4], inv_[4];
#pragma unroll
  for (int i = 0; i < 4; ++i) {
    int row = bm + wm + i * 16 + mr;
    float s0 = stats[2 * row], s1 = stats[2 * row + 1];
    float m = s0 * (1.f / kHA);
    mean_[i] = m;
    inv_[i] = rsqrtf(s1 * (1.f / kHA) - m * m + 1e-5f);
  }
  const int rkey = (mr >> 1) & 3;
  f32x4 acc[4][2] = {};
  __syncthreads();  // gb staged
  for (int k0 = 0; k0 < 512; k0 += 32) {
    if (k0) __syncthreads();
    load_lds16(Bg + k0, BsW);
    __syncthreads();
    const int kq = k0 + quad * 8;
    float4 gv0 = *(const float4*)&gb[kq];
    float4 gv1 = *(const float4*)&gb[kq + 4];
    float4 bv0 = *(const float4*)&gb[512 + kq];
    float4 bv1 = *(const float4*)&gb[512 + kq + 4];
    bf16x8 af[4];
#pragma unroll
    for (int i = 0; i < 4; ++i) {
      int row = bm + wm + i * 16 + mr;
      const float* sp = S + (size_t)row * 512 + kq;
      float4 a0 = *(const float4*)sp;
      float4 a1 = *(const float4*)(sp + 4);
      float m = mean_[i], rr = inv_[i];
      bf16x8 v;
      v[0] = (__bf16)((a0.x - m) * rr * gv0.x + bv0.x);
      v[1] = (__bf16)((a0.y - m) * rr * gv0.y + bv0.y);
      v[2] = (__bf16)((a0.z - m) * rr * gv0.z + bv0.z);
      v[3] = (__bf16)((a0.w - m) * rr * gv0.w + bv0.w);
      v[4] = (__bf16)((a1.x - m) * rr * gv1.x + bv1.x);
      v[5] = (__bf16)((a1.y - m) * rr * gv1.y + bv1.y);
      v[6] = (__bf16)((a1.z - m) * rr * gv1.z + bv1.z);
      v[7] = (__bf16)((a1.w - m) * rr * gv1.w + bv1.w);
      af[i] = v;
    }
    bf16x8 bfr[2];
#pragma unroll
    for (int j = 0; j < 2; ++j)
      bfr[j] = *(const bf16x8*)(Bs + (wn + j * 16 + mr) * 32 + (quad ^ rkey) * 8);
#pragma unroll
    for (int i = 0; i < 4; ++i)
#pragma unroll
      for (int j = 0; j < 2; ++j)
        acc[i][j] = __builtin_amdgcn_mfma_f32_16x16x32_bf16(af[i], bfr[j],
                                                            acc[i][j], 0, 0, 0);
  }
#pragma unroll
  for (int j = 0; j < 2; ++j) {
    int col = bn + wn + j * 16 + mr;
    float bs = bias[col];
#pragma unroll
    for (int i = 0; i < 4; ++i) {
      int row0 = bm + wm + i * 16 + quad * 4;
#pragma unroll
      for (int r = 0; r < 4; ++r) {
        float v = fmaxf(acc[i][j][r] + bs, 0.f);
        Cout[(size_t)(row0 + r) * 512 + col] = (__bf16)v;
      }
    }
  }
}

// ---------------- ff2 (plain) ----------------
__global__ __launch_bounds__(256) void gemm_ff2_kernel(
    const __bf16* __restrict__ A, const __bf16* __restrict__ Bt,
    const float* __restrict__ bias, __bf16* __restrict__ Cout) {
  __shared__ __bf16 smem[6144];
  gemm_core<64, 1, true, false, false>(blockIdx.x, blockIdx.y, A, Bt, bias,
                                       Cout, 512, 512, 512, smem, smem + 4096);
}

// ---------------- ff3: GEMM; epilogue S = LN1(S) + C + bias; atomic LN2 stats ----
__global__ __launch_bounds__(256) void ff3_res_gemm_kernel(
    const __bf16* __restrict__ A, const __bf16* __restrict__ Bt,
    const float* __restrict__ bias, float* __restrict__ S,
    const float* __restrict__ statsA, float* __restrict__ statsB,
    const float* __restrict__ g1, const float* __restrict__ b1) {
  __shared__ __bf16 As[128 * 32];
  __shared__ __bf16 Bs[64 * 32];
  __shared__ float gb1[128];
  const int t = threadIdx.x;
  const int wid = t >> 6, lane = t & 63;
  const int quad = lane >> 4, mr = lane & 15;
  const int bm = blockIdx.y * 128, bn = blockIdx.x * 64;
  const int wm = (wid >> 1) * 64, wn = (wid & 1) * 32;
  if (t < 64) {
    gb1[t] = g1[bn + t];
    gb1[64 + t] = b1[bn + t];
  }
  const int sr = lane >> 2, sc = lane & 3;
  const int skey = (sr >> 1) & 3;
  const __bf16* Ag = A + (size_t)(bm + wid * 32 + sr) * 512 + (sc ^ skey) * 8;
  const __bf16* Bg = Bt + (size_t)(bn + wid * 16 + sr) * 512 + (sc ^ skey) * 8;
  __bf16* AsW = As + (wid * 32) * 32;
  __bf16* BsW = Bs + (wid * 16) * 32;
  f32x4 acc[4][2] = {};
  const int rkey = (mr >> 1) & 3;
  for (int k0 = 0; k0 < 512; k0 += 32) {
    if (k0) __syncthreads();
    load_lds16(Ag + k0, AsW);
    load_lds16(Ag + (size_t)16 * 512 + k0, AsW + 16 * 32);
    load_lds16(Bg + k0, BsW);
    __syncthreads();
    bf16x8 af[4], bfr[2];
#pragma unroll
    for (int i = 0; i < 4; ++i)
      af[i] = *(const bf16x8*)(As + (wm + i * 16 + mr) * 32 + (quad ^ rkey) * 8);
#pragma unroll
    for (int j = 0; j < 2; ++j)
      bfr[j] = *(const bf16x8*)(Bs + (wn + j * 16 + mr) * 32 + (quad ^ rkey) * 8);
#pragma unroll
    for (int i = 0; i < 4; ++i)
#pragma unroll
      for (int j = 0; j < 2; ++j)
        acc[i][j] = __builtin_amdgcn_mfma_f32_16x16x32_bf16(af[i], bfr[j],
                                                            acc[i][j], 0, 0, 0);
  }
  // epilogue
#pragma unroll
  for (int i = 0; i < 4; ++i) {
    int row0 = bm + wm + i * 16 + quad * 4;
#pragma unroll
    for (int r = 0; r < 4; ++r) {
      int row = row0 + r;
      float s0 = statsA[2 * row], s1 = statsA[2 * row + 1];
      float m = s0 * (1.f / kHA);
      float inv = rsqrtf(s1 * (1.f / kHA) - m * m + 1e-5f);
      float ps = 0.f, pq = 0.f;
#pragma unroll
      for (int j = 0; j < 2; ++j) {
        int lc = wn + j * 16 + mr;
        int col = bn + lc;
        size_t idx = (size_t)row * 512 + col;
        float sval = S[idx];
        float resid = (sval - m) * inv * gb1[lc] + gb1[64 + lc];
        float v = resid + acc[i][j][r] + bias[col];
        S[idx] = v;
        ps += v;
        pq += v * v;
      }
      ps += __shfl_xor(ps, 1); pq += __shfl_xor(pq, 1);
      ps += __shfl_xor(ps, 2); pq += __shfl_xor(pq, 2);
      ps += __shfl_xor(ps, 4); pq += __shfl_xor(pq, 4);
      ps += __shfl_xor(ps, 8); pq += __shfl_xor(pq, 8);
      if (mr == 0) {
        atomicAdd(&statsB[2 * row], ps);
        atomicAdd(&statsB[2 * row + 1], pq);
      }
    }
  }
}

// ---------------- fused LN2 + de-projection + loss partials ----------------
__global__ __launch_bounds__(256) void de_loss_kernel(
    const float* __restrict__ S, const float* __restrict__ stats,
    const float* __restrict__ g2, const float* __restrict__ b2,
    const __bf16* __restrict__ de_wt, const float* __restrict__ de_b,
    const float* __restrict__ pred_u, float* __restrict__ parts) {
  __shared__ float gb[1024];
  const int blk = blockIdx.x;
  const int t = threadIdx.x;
  for (int i = t; i < 512; i += 256) {
    gb[i] = g2[i];
    gb[512 + i] = b2[i];
  }
  __syncthreads();
  const int w = t >> 6, lane = t & 63, quad = lane >> 4, mr = lane & 15;
  const int row0 = blk * 64 + w * 16;
  const int arow = row0 + mr;
  float s0 = stats[2 * arow], s1 = stats[2 * arow + 1];
  float m = s0 * (1.f / kHA);
  float inv = rsqrtf(s1 * (1.f / kHA) - m * m + 1e-5f);
  f32x4 acc[8] = {};
#pragma unroll 2
  for (int k0 = 0; k0 < 512; k0 += 32) {
    const int kq = k0 + quad * 8;
    const float* sp = S + (size_t)arow * 512 + kq;
    float4 a0 = *(const float4*)sp;
    float4 a1 = *(const float4*)(sp + 4);
    float4 gv0 = *(const float4*)&gb[kq];
    float4 gv1 = *(const float4*)&gb[kq + 4];
    float4 bv0 = *(const float4*)&gb[512 + kq];
    float4 bv1 = *(const float4*)&gb[512 + kq + 4];
    bf16x8 a;
    a[0] = (__bf16)((a0.x - m) * inv * gv0.x + bv0.x);
    a[1] = (__bf16)((a0.y - m) * inv * gv0.y + bv0.y);
    a[2] = (__bf16)((a0.z - m) * inv * gv0.z + bv0.z);
    a[3] = (__bf16)((a0.w - m) * inv * gv0.w + bv0.w);
    a[4] = (__bf16)((a1.x - m) * inv * gv1.x + bv1.x);
    a[5] = (__bf16)((a1.y - m) * inv * gv1.y + bv1.y);
    a[6] = (__bf16)((a1.z - m) * inv * gv1.z + bv1.z);
    a[7] = (__bf16)((a1.w - m) * inv * gv1.w + bv1.w);
#pragma unroll
    for (int j = 0; j < 8; ++j) {
      bf16x8 bb =
          *(const bf16x8*)(de_wt + (size_t)(j * 16 + mr) * 512 + k0 + quad * 8);
      acc[j] = __builtin_amdgcn_mfma_f32_16x16x32_bf16(a, bb, acc[j], 0, 0, 0);
    }
  }
  float dbv[8];
#pragma unroll
  for (int j = 0; j < 8; ++j) dbv[j] = de_b[j * 16 + mr];
  float lpacc = 0.f;
#pragma unroll
  for (int r = 0; r < 4; ++r) {
    int row = row0 + quad * 4 + r;
    int v = row & 255, bidx = row >> 8;
    float lg[8], mx = -1e30f;
#pragma unroll
    for (int j = 0; j < 8; ++j) {
      lg[j] = acc[j][r] + dbv[j];
      mx = fmaxf(mx, lg[j]);
    }
    mx = fmaxf(mx, __shfl_xor(mx, 1));
    mx = fmaxf(mx, __shfl_xor(mx, 2));
    mx = fmaxf(mx, __shfl_xor(mx, 4));
    mx = fmaxf(mx, __shfl_xor(mx, 8));
    float se = 0.f;
#pragma unroll
    for (int j = 0; j < 8; ++j) se += __expf(lg[j] - mx);
    se += __shfl_xor(se, 1);
    se += __shfl_xor(se, 2);
    se += __shfl_xor(se, 4);
    se += __shfl_xor(se, 8);
    float lse = mx + __logf(se);
    float u = pred_u[bidx * 256 + v];
    int tgt = (int)floorf(u * 128.f);
    tgt = max(0, min(127, tgt));
    float cand = (mr == (tgt & 15)) ? lg[tgt >> 4] : 0.f;
    cand += __shfl_xor(cand, 1);
    cand += __shfl_xor(cand, 2);
    cand += __shfl_xor(cand, 4);
    cand += __shfl_xor(cand, 8);
    float lp = (v >= 1) ? (4.8520302639196171f + cand - lse) : 0.f;  // ln(128)
    lpacc += lp;
  }
  lpacc += __shfl_xor(lpacc, 16);
  lpacc += __shfl_xor(lpacc, 32);
  __shared__ float red[4];
  if (lane == 0) red[w] = lpacc;
  __syncthreads();
  if (t == 0) parts[blk] = red[0] + red[1] + red[2] + red[3];
}

__global__ void loss_final_kernel(const float* __restrict__ parts,
                                  float* __restrict__ out) {
  int b = threadIdx.x;
  if (b < kB)
    out[b] = -(parts[b * 4] + parts[b * 4 + 1] + parts[b * 4 + 2] +
               parts[b * 4 + 3]);
}

extern "C" void kernel_launch(void* const* d_in, const int* in_sizes, int n_in,
                              void* d_out, int out_size, void* d_ws, size_t ws_size,
                              hipStream_t stream) {
  const float* hist   = (const float*)d_in[0];
  const float* hist_u = (const float*)d_in[1];
  const float* pred   = (const float*)d_in[2];
  const float* pred_u = (const float*)d_in[3];
  const float* ds_w   = (const float*)d_in[4];
  const float* ds_b   = (const float*)d_in[5];
  const float* key_w  = (const float*)d_in[6];
  const float* key_b  = (const float*)d_in[7];
  const float* val_w  = (const float*)d_in[8];
  const float* val_b  = (const float*)d_in[9];
  const float* ln1_g  = (const float*)d_in[10];
  const float* ln1_b  = (const float*)d_in[11];
  const float* ln2_g  = (const float*)d_in[12];
  const float* ln2_b  = (const float*)d_in[13];
  const float* ff_w1  = (const float*)d_in[14];
  const float* ff_b1  = (const float*)d_in[15];
  const float* ff_w2  = (const float*)d_in[16];
  const float* ff_b2  = (const float*)d_in[17];
  const float* ff_w3  = (const float*)d_in[18];
  const float* ff_b3  = (const float*)d_in[19];
  const float* de_w   = (const float*)d_in[20];
  const float* de_b   = (const float*)d_in[21];
  float* out = (float*)d_out;

  char* ws = (char*)d_ws;
  size_t off = 0;
  auto alloc = [&](size_t bytes) { char* p = ws + off; off += bytes; return p; };
  __bf16* ki_bf  = (__bf16*)alloc((size_t)kB * kW * kKP * 2);       // 7.1 MB
  __bf16* kv_wt  = (__bf16*)alloc((size_t)4096 * kKP * 2);          // 2.4 MB
  __bf16* ffw_t  = (__bf16*)alloc((size_t)12 * 512 * 512 * 2);      // 6.3 MB
  __bf16* ds_wt  = (__bf16*)alloc((size_t)512 * 256 * 2);
  __bf16* de_wt  = (__bf16*)alloc((size_t)128 * 512 * 2);
  float*  kvb    = (float*)alloc((size_t)4096 * 4);
  __bf16* kvs_k  = (__bf16*)alloc((size_t)kB * kW * 2048 * 2);      // 50.3 MB
  __bf16* vT     = (__bf16*)alloc((size_t)2048 * 12288 * 2);        // 50.3 MB
  float*  S      = (float*)alloc((size_t)kRows * kHA * 4);          // 8.4 MB
  float*  stats  = (float*)alloc((size_t)kP5 * 4);                  // 256 KB
  __bf16* ff1_bf = (__bf16*)alloc((size_t)kRows * kM * 2);
  __bf16* ff2_bf = (__bf16*)alloc((size_t)kRows * kM * 2);
  float*  parts  = (float*)alloc(64 * 4);

  prep_kernel<<<(kPT + 255) / 256, 256, 0, stream>>>(
      hist, hist_u, pred, pred_u, key_w, val_w, ff_w1, ff_w2, ff_w3, ds_w, de_w,
      key_b, val_b, ki_bf, kv_wt, ffw_t, ds_wt, de_wt, kvb, stats);

  // ds + keys + vT in one launch
  gemm3_kernel<<<3328, 256, 0, stream>>>(ki_bf, ds_wt, ds_b, S, kv_wt, kvb,
                                         kvs_k, vT);

  for (int l = 0; l < kL; ++l) {
    float* statsA = stats + l * 8192;                 // LN1 stats, layer l
    float* statsB = stats + 32768 + l * 8192;         // LN2 stats, layer l
    const float* statsPrev = stats + 32768 + (l - 1) * 8192;
    attn_kernel<<<dim3(kNV / 64, kH, kB), 256, 0, stream>>>(
        S, kvs_k, vT, (l > 0) ? statsPrev : stats, statsA,
        ln2_g + (l > 0 ? (l - 1) : 0) * kHA, ln2_b + (l > 0 ? (l - 1) : 0) * kHA,
        l);
    ff1_ln_gemm_kernel<<<dim3(kM / 64, kRows / 128), 256, 0, stream>>>(
        S, statsA, ln1_g + l * kHA, ln1_b + l * kHA,
        ffw_t + (size_t)(l * 3) * 262144, ff_b1 + l * kM, ff1_bf);
    gemm_ff2_kernel<<<dim3(kM / 64, kRows / 128), 256, 0, stream>>>(
        ff1_bf, ffw_t + (size_t)(l * 3 + 1) * 262144, ff_b2 + l * kM, ff2_bf);
    ff3_res_gemm_kernel<<<dim3(kHA / 64, kRows / 128), 256, 0, stream>>>(
        ff2_bf, ffw_t + (size_t)(l * 3 + 2) * 262144, ff_b3 + l * kHA, S,
        statsA, statsB, ln1_g + l * kHA, ln1_b + l * kHA);
  }
  de_loss_kernel<<<64, 256, 0, stream>>>(S, stats + 32768 + 3 * 8192,
                                         ln2_g + 3 * kHA, ln2_b + 3 * kHA, de_wt,
                                         de_b, pred_u, parts);
  loss_final_kernel<<<1, 64, 0, stream>>>(parts, out);
}

// Round 9
// 469.871 us; speedup vs baseline: 1.2289x; 1.2289x over previous
//
#include <hip/hip_runtime.h>

// Problem constants (AttentionalCopula)
constexpr int kB = 16, kD = 256, kNH = 512, kNV = 256, kW = 768;
constexpr int kL = 4, kH = 8, kA = 64, kHA = 512, kM = 512, kR = 128;
constexpr int kKP = 288;  // K=257 zero-padded to multiple of 32
constexpr int kRows = kB * kNV;  // 4096

typedef __bf16 bf16x8 __attribute__((ext_vector_type(8)));
typedef __bf16 bf16x4 __attribute__((ext_vector_type(4)));
typedef float f32x4 __attribute__((ext_vector_type(4)));

__device__ inline void load_lds16(const __bf16* g, __bf16* l) {
  __builtin_amdgcn_global_load_lds(
      (const __attribute__((address_space(1))) void*)g,
      (__attribute__((address_space(3))) void*)l, 16, 0, 0);
}

// ---------------- merged prep kernel (1 launch) ----------------
constexpr int kP1 = kB * kW * kKP;        // ki
constexpr int kP2 = 4096 * kKP;           // kv weights
constexpr int kP3 = 12 * 512 * 512;       // ff weights
constexpr int kP4 = 200704;               // ds_wt, de_wt, kvb
constexpr int kP5 = 16;                   // zero d_out
constexpr int kPT = kP1 + kP2 + kP3 + kP4 + kP5;

__global__ void prep_kernel(const float* __restrict__ hist,
                            const float* __restrict__ hist_u,
                            const float* __restrict__ pred,
                            const float* __restrict__ pred_u,
                            const float* __restrict__ kw,
                            const float* __restrict__ vw,
                            const float* __restrict__ w1,
                            const float* __restrict__ w2,
                            const float* __restrict__ w3,
                            const float* __restrict__ ds_w,
                            const float* __restrict__ de_w,
                            const float* __restrict__ key_b,
                            const float* __restrict__ val_b,
                            __bf16* __restrict__ ki,
                            __bf16* __restrict__ kvwt,
                            __bf16* __restrict__ ffwt,
                            __bf16* __restrict__ ds_wt,
                            __bf16* __restrict__ de_wt,
                            float* __restrict__ kvb,
                            float* __restrict__ outz) {
  int i = blockIdx.x * 256 + threadIdx.x;
  if (i < kP1) {
    int d = i % kKP;
    int bw = i / kKP;
    int w = bw % kW;
    int b = bw / kW;
    float v = 0.f;
    if (d < 257) {
      if (w < kNH)
        v = (d < kD) ? hist[((size_t)b * kNH + w) * kD + d] : hist_u[b * kNH + w];
      else {
        int p = w - kNH;
        v = (d < kD) ? pred[((size_t)b * kNV + p) * kD + d] : pred_u[b * kNV + p];
      }
    }
    ki[i] = (__bf16)v;
  } else if (i < kP1 + kP2) {
    int j = i - kP1;
    int d = j % kKP;
    int c = j / kKP;
    float v = 0.f;
    if (d < 257) {
      bool isv = c >= 2048;
      int cc = isv ? c - 2048 : c;
      int l = cc >> 9, rest = cc & 511;
      int h = rest >> 6, a = rest & 63;
      size_t src = (((size_t)l * kH + h) * 257 + d) * kA + a;
      v = isv ? vw[src] : kw[src];
    }
    kvwt[j] = (__bf16)v;
  } else if (i < kP1 + kP2 + kP3) {
    int j = i - kP1 - kP2;
    int k = j & 511;
    int n = (j >> 9) & 511;
    int mat = j >> 18;
    int l = mat / 3, which = mat % 3;
    const float* src = which == 0 ? w1 : which == 1 ? w2 : w3;
    ffwt[j] = (__bf16)src[((size_t)l * 512 + k) * 512 + n];
  } else if (i < kP1 + kP2 + kP3 + kP4) {
    int j = i - kP1 - kP2 - kP3;
    if (j < 131072) {
      int n = j >> 8, k = j & 255;
      ds_wt[j] = (__bf16)ds_w[k * 512 + n];
    } else if (j < 196608) {
      int jj = j - 131072;
      int n = jj >> 9, k = jj & 511;
      de_wt[jj] = (__bf16)de_w[k * 128 + n];
    } else {
      int c = j - 196608;  // 0..4095
      bool isv = c >= 2048;
      int cc = isv ? c - 2048 : c;
      int l = cc >> 9, rest = cc & 511;
      kvb[c] = isv ? val_b[l * 512 + rest] : key_b[l * 512 + rest];
    }
  } else if (i < kPT) {
    outz[i - kP1 - kP2 - kP3 - kP4] = 0.f;
  }
}

// ---------------- generic bf16 MFMA GEMM core ----------------
// OMODE: 0=f32 out, 1=bf16 out, 2=both. XOR-swizzled LDS. KIMAP: A rows
// remap r -> (r>>8)*768 + 512 + (r&255). BIASROW: bias indexed by row.
template <int BN, int OMODE, bool RELU, bool KIMAP, bool BIASROW>
__device__ __forceinline__ void gemm_core(
    int bxv, int byv, const __bf16* __restrict__ A,
    const __bf16* __restrict__ Bt, const float* __restrict__ bias,
    void* __restrict__ Cout, __bf16* __restrict__ Cout2, int K, int lda,
    int ldc, __bf16* As, __bf16* Bs) {
  constexpr int JN = BN / 32;
  constexpr int BROWS = BN / 4;
  const int t = threadIdx.x;
  const int wid = t >> 6;
  const int lane = t & 63;
  const int bm = byv * 128;
  const int bn = bxv * BN;
  const int wm = (wid >> 1) * 64;
  const int wn = (wid & 1) * (BN / 2);
  const int sr = lane >> 2, sc = lane & 3;
  const int skey = (sr >> 1) & 3;
  const int abase = KIMAP ? ((bm >> 8) * 768 + 512 + (bm & 255)) : bm;
  const __bf16* Ag = A + (size_t)(abase + wid * 32 + sr) * lda + (sc ^ skey) * 8;
  const __bf16* Bg = Bt + (size_t)(bn + wid * BROWS + sr) * K + (sc ^ skey) * 8;
  __bf16* AsW = As + (wid * 32) * 32;
  __bf16* BsW = Bs + (wid * BROWS) * 32;

  f32x4 acc[4][JN] = {};
  const int q = lane >> 4, mr = lane & 15;
  const int rkey = (mr >> 1) & 3;
  for (int k0 = 0; k0 < K; k0 += 32) {
    if (k0) __syncthreads();
    load_lds16(Ag + k0, AsW);
    load_lds16(Ag + (size_t)16 * lda + k0, AsW + 16 * 32);
    load_lds16(Bg + k0, BsW);
    if (BN == 128) load_lds16(Bg + (size_t)16 * K + k0, BsW + 16 * 32);
    __syncthreads();
    bf16x8 af[4], bfr[JN];
#pragma unroll
    for (int i = 0; i < 4; ++i)
      af[i] = *(const bf16x8*)(As + (wm + i * 16 + mr) * 32 + (q ^ rkey) * 8);
#pragma unroll
    for (int j = 0; j < JN; ++j)
      bfr[j] = *(const bf16x8*)(Bs + (wn + j * 16 + mr) * 32 + (q ^ rkey) * 8);
#pragma unroll
    for (int i = 0; i < 4; ++i)
#pragma unroll
      for (int j = 0; j < JN; ++j)
        acc[i][j] = __builtin_amdgcn_mfma_f32_16x16x32_bf16(af[i], bfr[j],
                                                            acc[i][j], 0, 0, 0);
  }
#pragma unroll
  for (int j = 0; j < JN; ++j) {
    int col = bn + wn + j * 16 + mr;
    float bscol = BIASROW ? 0.f : bias[col];
#pragma unroll
    for (int i = 0; i < 4; ++i) {
      int row0 = bm + wm + i * 16 + q * 4;
#pragma unroll
      for (int r = 0; r < 4; ++r) {
        float v = acc[i][j][r] + (BIASROW ? bias[row0 + r] : bscol);
        if (RELU) v = fmaxf(v, 0.f);
        size_t idx = (size_t)(row0 + r) * ldc + col;
        if (OMODE == 0) {
          ((float*)Cout)[idx] = v;
        } else if (OMODE == 1) {
          ((__bf16*)Cout)[idx] = (__bf16)v;
        } else {
          ((float*)Cout)[idx] = v;
          Cout2[idx] = (__bf16)v;
        }
      }
    }
  }
}

// ---------------- fused ds + keys + vT GEMM (one launch, 3328 blocks) ----------------
__global__ __launch_bounds__(256) void gemm3_kernel(
    const __bf16* __restrict__ ki, const __bf16* __restrict__ ds_wt,
    const float* __restrict__ ds_b, float* __restrict__ att,
    __bf16* __restrict__ att_bf, const __bf16* __restrict__ kv_wt,
    const float* __restrict__ kvb, __bf16* __restrict__ kvs_k,
    __bf16* __restrict__ vT) {
  __shared__ __bf16 smem[8192];
  __bf16* As = smem;
  __bf16* Bs = smem + 4096;
  int bid = blockIdx.x;
  if (bid < 256) {
    // ds: att(+bf) = pred @ ds_w + b  [4096 x 512], K=256, A rows inside ki
    gemm_core<64, 2, false, true, false>(bid & 7, bid >> 3, ki, ds_wt, ds_b,
                                         att, att_bf, 256, kKP, 512, As, Bs);
  } else if (bid < 1792) {
    // keys: [12288 x 2048]
    int b2 = bid - 256;
    gemm_core<128, 1, false, false, false>(b2 & 15, b2 >> 4, ki, kv_wt, kvb,
                                           kvs_k, nullptr, kKP, kKP, 2048, As,
                                           Bs);
  } else {
    // values^T: [2048 x 12288] = Wv^T @ ki^T (bias per row)
    int b3 = bid - 1792;
    gemm_core<128, 1, false, false, true>(b3 % 96, b3 / 96,
                                          kv_wt + (size_t)2048 * kKP, ki,
                                          kvb + 2048, vT, nullptr, kKP, kKP,
                                          12288, As, Bs);
  }
}

// ---------------- ff GEMMs (gemm_core wrappers) ----------------
template <bool RELU>
__global__ __launch_bounds__(256) void gemm_ff_kernel(
    const __bf16* __restrict__ A, const __bf16* __restrict__ Bt,
    const float* __restrict__ bias, __bf16* __restrict__ Cout) {
  __shared__ __bf16 smem[6144];
  gemm_core<64, 1, RELU, false, false>(blockIdx.x, blockIdx.y, A, Bt, bias,
                                       Cout, nullptr, 512, 512, 512, smem,
                                       smem + 4096);
}

// ---------------- MFMA flash attention (S^T variant, reg-prefetched) ----------------
__global__ __launch_bounds__(256) void attn_mfma_kernel(
    const __bf16* __restrict__ attbf, const __bf16* __restrict__ kvs_k,
    const __bf16* __restrict__ vT, __bf16* __restrict__ outbf, int l) {
  const int b = blockIdx.z, h = blockIdx.y, qt = blockIdx.x;
  __shared__ __bf16 Ks[64 * 72];
  __shared__ __bf16 Vt[64 * 72];
  __shared__ __bf16 Ps[64 * 72];
  const int t = threadIdx.x;
  const int w = t >> 6, lane = t & 63;
  const int quad = lane >> 4, mr = lane & 15;
  bf16x8 aq[2];
  {
    const __bf16* qp = attbf + ((size_t)(b * kNV + qt * 64 + w * 16 + mr) * kHA +
                                h * kA + quad * 8);
    aq[0] = *(const bf16x8*)qp;
    aq[1] = *(const bf16x8*)(qp + 32);
  }
  f32x4 o[4] = {};
  float m_ = -1e30f, l_ = 0.f;
  const int cmax = kNH + qt * 64;
  const int pr = t >> 2, pc = t & 3;
  const __bf16* kbase = kvs_k + ((size_t)(b * kW + pr) * 2048 + l * 512 + h * kA);
  const __bf16* vbase = vT + (size_t)(l * 512 + h * kA + pr) * 12288 + b * kW;
  bf16x8 kc0, kc1, vc0, vc1;
  kc0 = *(const bf16x8*)(kbase + pc * 8);
  kc1 = *(const bf16x8*)(kbase + pc * 8 + 32);
  vc0 = *(const bf16x8*)(vbase + pc * 16);
  vc1 = *(const bf16x8*)(vbase + pc * 16 + 8);
  for (int c0 = 0; c0 <= cmax; c0 += 64) {
    __syncthreads();
    *(bf16x8*)&Ks[pr * 72 + pc * 8] = kc0;
    *(bf16x8*)&Ks[pr * 72 + pc * 8 + 32] = kc1;
    *(bf16x8*)&Vt[pr * 72 + pc * 16] = vc0;
    *(bf16x8*)&Vt[pr * 72 + pc * 16 + 8] = vc1;
    __syncthreads();
    if (c0 + 64 <= cmax) {
      const __bf16* kp = kbase + (size_t)(c0 + 64) * 2048;
      const __bf16* vp = vbase + c0 + 64;
      kc0 = *(const bf16x8*)(kp + pc * 8);
      kc1 = *(const bf16x8*)(kp + pc * 8 + 32);
      vc0 = *(const bf16x8*)(vp + pc * 16);
      vc1 = *(const bf16x8*)(vp + pc * 16 + 8);
    }
    // ---- S^T = K·Q^T ----
    f32x4 s[4];
#pragma unroll
    for (int j = 0; j < 4; ++j) {
      bf16x8 ak0 = *(const bf16x8*)&Ks[(j * 16 + mr) * 72 + quad * 8];
      bf16x8 ak1 = *(const bf16x8*)&Ks[(j * 16 + mr) * 72 + quad * 8 + 32];
      f32x4 z = {};
      z = __builtin_amdgcn_mfma_f32_16x16x32_bf16(ak0, aq[0], z, 0, 0, 0);
      z = __builtin_amdgcn_mfma_f32_16x16x32_bf16(ak1, aq[1], z, 0, 0, 0);
      s[j] = z;
    }
    const int lim = cmax - c0;
    float sv[16], mx = -1e30f;
#pragma unroll
    for (int j = 0; j < 4; ++j)
#pragma unroll
      for (int r = 0; r < 4; ++r) {
        int p = j * 16 + quad * 4 + r;
        float x = (p < lim + mr) ? s[j][r] * 0.125f : -1e30f;
        sv[j * 4 + r] = x;
        mx = fmaxf(mx, x);
      }
    mx = fmaxf(mx, __shfl_xor(mx, 16));
    mx = fmaxf(mx, __shfl_xor(mx, 32));
    float mnew = fmaxf(m_, mx);
    float corr = __expf(m_ - mnew);
    float rs = 0.f;
#pragma unroll
    for (int i = 0; i < 16; ++i) {
      sv[i] = __expf(sv[i] - mnew);
      rs += sv[i];
    }
    rs += __shfl_xor(rs, 16);
    rs += __shfl_xor(rs, 32);
    l_ = l_ * corr + rs;
    m_ = mnew;
#pragma unroll
    for (int j = 0; j < 4; ++j) {
      bf16x4 pk = {(__bf16)sv[j * 4 + 0], (__bf16)sv[j * 4 + 1],
                   (__bf16)sv[j * 4 + 2], (__bf16)sv[j * 4 + 3]};
      *(bf16x4*)&Ps[(w * 16 + mr) * 72 + j * 16 + quad * 4] = pk;
    }
#pragma unroll
    for (int r = 0; r < 4; ++r) {
      float cr = __shfl(corr, quad * 4 + r);
#pragma unroll
      for (int j = 0; j < 4; ++j) o[j][r] *= cr;
    }
    bf16x8 ap0 = *(const bf16x8*)&Ps[(w * 16 + mr) * 72 + quad * 8];
    bf16x8 ap1 = *(const bf16x8*)&Ps[(w * 16 + mr) * 72 + quad * 8 + 32];
#pragma unroll
    for (int j = 0; j < 4; ++j) {
      bf16x8 b0 = *(const bf16x8*)&Vt[(j * 16 + mr) * 72 + quad * 8];
      bf16x8 b1 = *(const bf16x8*)&Vt[(j * 16 + mr) * 72 + quad * 8 + 32];
      o[j] = __builtin_amdgcn_mfma_f32_16x16x32_bf16(ap0, b0, o[j], 0, 0, 0);
      o[j] = __builtin_amdgcn_mfma_f32_16x16x32_bf16(ap1, b1, o[j], 0, 0, 0);
    }
  }
  float invl = 1.f / l_;
#pragma unroll
  for (int r = 0; r < 4; ++r) {
    float ir = __shfl(invl, quad * 4 + r);
    int row = b * kNV + qt * 64 + w * 16 + quad * 4 + r;
#pragma unroll
    for (int j = 0; j < 4; ++j)
      outbf[(size_t)row * kHA + h * kA + j * 16 + mr] = (__bf16)(o[j][r] * ir);
  }
}

// ---------------- att = LN(att + add_bf); emits bf16 copy ----------------
__global__ __launch_bounds__(128) void add_ln_kernel(
    float* __restrict__ att, const __bf16* __restrict__ addbf,
    const float* __restrict__ g, const float* __restrict__ be,
    __bf16* __restrict__ attbf) {
  const int row = blockIdx.x;
  const int t = threadIdx.x;
  float4* ar = (float4*)(att + (size_t)row * kHA);
  bf16x4 dv = *(const bf16x4*)(addbf + (size_t)row * kHA + t * 4);
  float4 x = ar[t];
  x.x += (float)dv[0]; x.y += (float)dv[1];
  x.z += (float)dv[2]; x.w += (float)dv[3];
  float s = x.x + x.y + x.z + x.w;
  float sq = x.x * x.x + x.y * x.y + x.z * x.z + x.w * x.w;
  for (int o = 32; o; o >>= 1) {
    s += __shfl_xor(s, o);
    sq += __shfl_xor(sq, o);
  }
  __shared__ float red[4];
  if ((t & 63) == 0) { red[(t >> 6) * 2] = s; red[(t >> 6) * 2 + 1] = sq; }
  __syncthreads();
  float S = red[0] + red[2], Q = red[1] + red[3];
  float mean = S * (1.f / kHA);
  float inv = rsqrtf(Q * (1.f / kHA) - mean * mean + 1e-5f);
  float4 gv = ((const float4*)g)[t];
  float4 bv = ((const float4*)be)[t];
  float4 y;
  y.x = gv.x * (x.x - mean) * inv + bv.x;
  y.y = gv.y * (x.y - mean) * inv + bv.y;
  y.z = gv.z * (x.z - mean) * inv + bv.z;
  y.w = gv.w * (x.w - mean) * inv + bv.w;
  ar[t] = y;
  bf16x4 yb = {(__bf16)y.x, (__bf16)y.y, (__bf16)y.z, (__bf16)y.w};
  *(bf16x4*)(attbf + (size_t)row * kHA + t * 4) = yb;
}

// ---------------- fused de-projection + loss (atomic into out) ----------------
__global__ __launch_bounds__(256) void de_loss_kernel(
    const __bf16* __restrict__ attbf, const __bf16* __restrict__ de_wt,
    const float* __restrict__ de_b, const float* __restrict__ pred_u,
    float* __restrict__ out) {
  const int blk = blockIdx.x;
  const int t = threadIdx.x;
  const int w = t >> 6, lane = t & 63, quad = lane >> 4, mr = lane & 15;
  const int row0 = blk * 64 + w * 16;
  f32x4 acc[8] = {};
  const __bf16* Ap = attbf + (size_t)(row0 + mr) * kHA + quad * 8;
#pragma unroll 4
  for (int k0 = 0; k0 < 512; k0 += 32) {
    bf16x8 a = *(const bf16x8*)(Ap + k0);
#pragma unroll
    for (int j = 0; j < 8; ++j) {
      bf16x8 bb =
          *(const bf16x8*)(de_wt + (size_t)(j * 16 + mr) * 512 + k0 + quad * 8);
      acc[j] = __builtin_amdgcn_mfma_f32_16x16x32_bf16(a, bb, acc[j], 0, 0, 0);
    }
  }
  float dbv[8];
#pragma unroll
  for (int j = 0; j < 8; ++j) dbv[j] = de_b[j * 16 + mr];
  float lpacc = 0.f;
#pragma unroll
  for (int r = 0; r < 4; ++r) {
    int row = row0 + quad * 4 + r;
    int v = row & 255;
    float lg[8], mx = -1e30f;
#pragma unroll
    for (int j = 0; j < 8; ++j) {
      lg[j] = acc[j][r] + dbv[j];
      mx = fmaxf(mx, lg[j]);
    }
    mx = fmaxf(mx, __shfl_xor(mx, 1));
    mx = fmaxf(mx, __shfl_xor(mx, 2));
    mx = fmaxf(mx, __shfl_xor(mx, 4));
    mx = fmaxf(mx, __shfl_xor(mx, 8));
    float se = 0.f;
#pragma unroll
    for (int j = 0; j < 8; ++j) se += __expf(lg[j] - mx);
    se += __shfl_xor(se, 1);
    se += __shfl_xor(se, 2);
    se += __shfl_xor(se, 4);
    se += __shfl_xor(se, 8);
    float lse = mx + __logf(se);
    float u = pred_u[(row >> 8) * 256 + v];
    int tgt = (int)floorf(u * 128.f);
    tgt = max(0, min(127, tgt));
    float cand = (mr == (tgt & 15)) ? lg[tgt >> 4] : 0.f;
    cand += __shfl_xor(cand, 1);
    cand += __shfl_xor(cand, 2);
    cand += __shfl_xor(cand, 4);
    cand += __shfl_xor(cand, 8);
    float lp = (v >= 1) ? (4.8520302639196171f + cand - lse) : 0.f;  // ln(128)
    lpacc += lp;
  }
  lpacc += __shfl_xor(lpacc, 16);
  lpacc += __shfl_xor(lpacc, 32);
  __shared__ float red[4];
  if (lane == 0) red[w] = lpacc;
  __syncthreads();
  if (t == 0)
    atomicAdd(&out[blk >> 2], -(red[0] + red[1] + red[2] + red[3]));
}

extern "C" void kernel_launch(void* const* d_in, const int* in_sizes, int n_in,
                              void* d_out, int out_size, void* d_ws, size_t ws_size,
                              hipStream_t stream) {
  const float* hist   = (const float*)d_in[0];
  const float* hist_u = (const float*)d_in[1];
  const float* pred   = (const float*)d_in[2];
  const float* pred_u = (const float*)d_in[3];
  const float* ds_w   = (const float*)d_in[4];
  const float* ds_b   = (const float*)d_in[5];
  const float* key_w  = (const float*)d_in[6];
  const float* key_b  = (const float*)d_in[7];
  const float* val_w  = (const float*)d_in[8];
  const float* val_b  = (const float*)d_in[9];
  const float* ln1_g  = (const float*)d_in[10];
  const float* ln1_b  = (const float*)d_in[11];
  const float* ln2_g  = (const float*)d_in[12];
  const float* ln2_b  = (const float*)d_in[13];
  const float* ff_w1  = (const float*)d_in[14];
  const float* ff_b1  = (const float*)d_in[15];
  const float* ff_w2  = (const float*)d_in[16];
  const float* ff_b2  = (const float*)d_in[17];
  const float* ff_w3  = (const float*)d_in[18];
  const float* ff_b3  = (const float*)d_in[19];
  const float* de_w   = (const float*)d_in[20];
  const float* de_b   = (const float*)d_in[21];
  float* out = (float*)d_out;

  char* ws = (char*)d_ws;
  size_t off = 0;
  auto alloc = [&](size_t bytes) { char* p = ws + off; off += bytes; return p; };
  __bf16* ki_bf  = (__bf16*)alloc((size_t)kB * kW * kKP * 2);       // 7.1 MB
  __bf16* kv_wt  = (__bf16*)alloc((size_t)4096 * kKP * 2);          // 2.4 MB
  __bf16* ffw_t  = (__bf16*)alloc((size_t)12 * 512 * 512 * 2);      // 6.3 MB
  __bf16* ds_wt  = (__bf16*)alloc((size_t)512 * 256 * 2);
  __bf16* de_wt  = (__bf16*)alloc((size_t)128 * 512 * 2);
  float*  kvb    = (float*)alloc((size_t)4096 * 4);
  __bf16* kvs_k  = (__bf16*)alloc((size_t)kB * kW * 2048 * 2);      // 50.3 MB
  __bf16* vT     = (__bf16*)alloc((size_t)2048 * 12288 * 2);        // 50.3 MB
  float*  att    = (float*)alloc((size_t)kRows * kHA * 4);          // 8.4 MB
  __bf16* att_bf = (__bf16*)alloc((size_t)kRows * kHA * 2);
  __bf16* tmp_bf = (__bf16*)alloc((size_t)kRows * kHA * 2);
  __bf16* ff1_bf = (__bf16*)alloc((size_t)kRows * kM * 2);
  __bf16* ff2_bf = (__bf16*)alloc((size_t)kRows * kM * 2);

  prep_kernel<<<(kPT + 255) / 256, 256, 0, stream>>>(
      hist, hist_u, pred, pred_u, key_w, val_w, ff_w1, ff_w2, ff_w3, ds_w, de_w,
      key_b, val_b, ki_bf, kv_wt, ffw_t, ds_wt, de_wt, kvb, out);

  // ds + keys + vT in one launch
  gemm3_kernel<<<3328, 256, 0, stream>>>(ki_bf, ds_wt, ds_b, att, att_bf, kv_wt,
                                         kvb, kvs_k, vT);

  for (int l = 0; l < kL; ++l) {
    attn_mfma_kernel<<<dim3(kNV / 64, kH, kB), 256, 0, stream>>>(
        att_bf, kvs_k, vT, tmp_bf, l);
    add_ln_kernel<<<kRows, 128, 0, stream>>>(att, tmp_bf, ln1_g + l * kHA,
                                             ln1_b + l * kHA, att_bf);
    gemm_ff_kernel<true><<<dim3(kM / 64, kRows / 128), 256, 0, stream>>>(
        att_bf, ffw_t + (size_t)(l * 3) * 262144, ff_b1 + l * kM, ff1_bf);
    gemm_ff_kernel<true><<<dim3(kM / 64, kRows / 128), 256, 0, stream>>>(
        ff1_bf, ffw_t + (size_t)(l * 3 + 1) * 262144, ff_b2 + l * kM, ff2_bf);
    gemm_ff_kernel<false><<<dim3(kHA / 64, kRows / 128), 256, 0, stream>>>(
        ff2_bf, ffw_t + (size_t)(l * 3 + 2) * 262144, ff_b3 + l * kHA, tmp_bf);
    add_ln_kernel<<<kRows, 128, 0, stream>>>(att, tmp_bf, ln2_g + l * kHA,
                                             ln2_b + l * kHA, att_bf);
  }
  de_loss_kernel<<<64, 256, 0, stream>>>(att_bf, de_wt, de_b, pred_u, out);
}